// Round 1
// baseline (246.304 us; speedup 1.0000x reference)
//
#include <hip/hip_runtime.h>
#include <hip/hip_bf16.h>
#include <stdint.h>

// MHA: out = softmax_mask((X Wq)(X Wk)^T / sqrt(dh)) (X Wv), per-head, per-query valid_len mask.
// B=8 S=1024 D=1024 H=16 DH=64. f32 in/out, bf16 MFMA internally.

#define B_  8
#define S_  1024
#define D_  1024
#define H_  16
#define DH_ 64

typedef short bf16x8 __attribute__((ext_vector_type(8)));
typedef float f32x4  __attribute__((ext_vector_type(4)));
typedef unsigned short u16;
typedef u16 u16x8 __attribute__((ext_vector_type(8)));
typedef u16 u16x4 __attribute__((ext_vector_type(4)));

__device__ __forceinline__ u16 f2bf(float f) {
    union { float f; uint32_t u; } v; v.f = f;
    uint32_t u = v.u;
    return (u16)((u + 0x7FFFu + ((u >> 16) & 1u)) >> 16);   // RNE
}

__device__ __forceinline__ void gload16(const void* g, const void* l) {
    __builtin_amdgcn_global_load_lds(
        (const __attribute__((address_space(1))) void*)g,
        (__attribute__((address_space(3))) void*)l, 16, 0, 0);
}

// ---------------- f32 -> bf16 elementwise convert (vectorized, G13) ----------------
__global__ void cvt_bf16_kernel(const float* __restrict__ in, u16* __restrict__ out, int n8) {
    int i = blockIdx.x * blockDim.x + threadIdx.x;
    if (i >= n8) return;
    const float4* p = (const float4*)in + (size_t)i * 2;
    float4 a = p[0], b = p[1];
    u16x8 r;
    r[0] = f2bf(a.x); r[1] = f2bf(a.y); r[2] = f2bf(a.z); r[3] = f2bf(a.w);
    r[4] = f2bf(b.x); r[5] = f2bf(b.y); r[6] = f2bf(b.z); r[7] = f2bf(b.w);
    *((u16x8*)out + i) = r;
}

// ---------------- W[k][n] f32 -> Wt[n][k] bf16 (LDS-tiled transpose) ----------------
__global__ void transpose_w_kernel(const float* __restrict__ W, u16* __restrict__ Wt) {
    __shared__ u16 tile[32 * 33];
    int k0 = blockIdx.y * 32, n0 = blockIdx.x * 32;
    int t = threadIdx.x;
    int c = t & 31;
    for (int p = 0; p < 4; ++p) {
        int r = p * 8 + (t >> 5);
        tile[r * 33 + c] = f2bf(W[(size_t)(k0 + r) * D_ + n0 + c]);
    }
    __syncthreads();
    int rn = t >> 3, c4 = t & 7;
    u16x4 v;
    for (int j = 0; j < 4; ++j) v[j] = tile[(c4 * 4 + j) * 33 + rn];
    *(u16x4*)(Wt + (size_t)(n0 + rn) * D_ + k0 + c4 * 4) = v;
}

// ---------------- bf16 GEMM: C[M=8192][1024] = A[8192][1024] * Wt[1024][1024]^T ----------------
// m97 structure: 128x128 tile, BK=32, 4 waves each 64x64, global_load_lds(16B), 16 MFMA/K-step.
__global__ __launch_bounds__(256) void gemm_bf16_kernel(const u16* __restrict__ A,
                                                        const u16* __restrict__ Bt,
                                                        u16* __restrict__ C) {
    __shared__ u16 lds_a[2][128 * 32];
    __shared__ u16 lds_b[2][128 * 32];
    const int t = threadIdx.x, w = t >> 6, l = t & 63;
    const int m0 = blockIdx.x * 128, n0 = blockIdx.y * 128;
    const int wr = w >> 1, wc = w & 1;
    const int l15 = l & 15, l4 = l >> 4;
    f32x4 acc[4][4] = {};

    auto stage = [&](int buf, int kt) {
        int k0 = kt * 32;
        for (int i = 0; i < 2; ++i) {
            int ch = w * 64 + i * 256 + l;
            int row = ch >> 2, x = ch & 3;
            gload16(A + (size_t)(m0 + row) * D_ + k0 + x * 8,
                    &lds_a[buf][(w * 64 + i * 256) * 8]);
        }
        for (int i = 0; i < 2; ++i) {
            int ch = w * 64 + i * 256 + l;
            int row = ch >> 2, x = ch & 3;
            gload16(Bt + (size_t)(n0 + row) * D_ + k0 + x * 8,
                    &lds_b[buf][(w * 64 + i * 256) * 8]);
        }
    };

    stage(0, 0);
    __syncthreads();
    int buf = 0;
    for (int kt = 0; kt < 32; ++kt) {
        if (kt + 1 < 32) stage(buf ^ 1, kt + 1);
        bf16x8 af[4], bfr[4];
        for (int mi = 0; mi < 4; ++mi)
            af[mi] = *(const bf16x8*)&lds_a[buf][(wr * 64 + mi * 16 + l15) * 32 + l4 * 8];
        for (int ni = 0; ni < 4; ++ni)
            bfr[ni] = *(const bf16x8*)&lds_b[buf][(wc * 64 + ni * 16 + l15) * 32 + l4 * 8];
        for (int mi = 0; mi < 4; ++mi)
            for (int ni = 0; ni < 4; ++ni)
                acc[mi][ni] = __builtin_amdgcn_mfma_f32_16x16x32_bf16(af[mi], bfr[ni], acc[mi][ni], 0, 0, 0);
        __syncthreads();
        buf ^= 1;
    }
    // epilogue: C/D layout col=lane&15, row=(lane>>4)*4+reg (m89-verified)
    for (int mi = 0; mi < 4; ++mi)
        for (int ni = 0; ni < 4; ++ni)
            for (int r = 0; r < 4; ++r) {
                int m = m0 + wr * 64 + mi * 16 + l4 * 4 + r;
                int n = n0 + wc * 64 + ni * 16 + l15;
                C[(size_t)m * D_ + n] = f2bf(acc[mi][ni][r]);
            }
}

// ---------------- vb [B,S,H,DH] -> vt [B,H,DH,S] (per-head transpose) ----------------
__global__ void transpose_v_kernel(const u16* __restrict__ vb, u16* __restrict__ vt) {
    __shared__ u16 t2[64 * 72];
    int bid = blockIdx.x;            // ((b*H + h)*16 + st)
    int st = bid & 15, bh = bid >> 4;
    int b = bh >> 4, h = bh & 15;
    int t = threadIdx.x;
    for (int p = 0; p < 2; ++p) {
        int c = p * 256 + t, r = c >> 3, x = c & 7;
        u16x8 val = *(const u16x8*)&vb[((size_t)(b * S_ + st * 64 + r)) * D_ + h * 64 + x * 8];
        *(u16x8*)&t2[r * 72 + x * 8] = val;
    }
    __syncthreads();
    int d = t >> 2, kc = t & 3;
    u16x8 o0, o1;
    for (int j = 0; j < 8; ++j) o0[j] = t2[(kc * 16 + j) * 72 + d];
    for (int j = 0; j < 8; ++j) o1[j] = t2[(kc * 16 + 8 + j) * 72 + d];
    size_t obase = ((size_t)bh * 64 + d) * (size_t)S_ + st * 64 + kc * 16;
    *(u16x8*)&vt[obase] = o0;
    *(u16x8*)&vt[obase + 8] = o1;
}

// ---------------- flash attention ----------------
// grid (B*H, S/64); 4 waves, each owns 16 q-rows. K & Vt tiles staged via global_load_lds
// with pre-swizzled SOURCE (m173) so 128B-row LDS reads are XOR-swizzled conflict-free (G4).
__global__ __launch_bounds__(256) void attn_kernel(const u16* __restrict__ qb,
                                                   const u16* __restrict__ kb,
                                                   const u16* __restrict__ vt,
                                                   const int* __restrict__ vlen,
                                                   float* __restrict__ out) {
    __shared__ u16 k_lds[64 * 64];   // [krow][d], swizzled chunks
    __shared__ u16 v_lds[64 * 64];   // [d][k],   swizzled chunks
    __shared__ u16 p_lds[4 * 16 * 64]; // per-wave P[16][64], swizzled

    const int t = threadIdx.x, w = t >> 6, l = t & 63;
    const int bh = blockIdx.x, b = bh >> 4, h = bh & 15;
    const int q0 = blockIdx.y * 64;
    const int l15 = l & 15, l4 = l >> 4;

    // Q A-fragments (hoisted; A layout: row=l&15, k=(l>>4)*8+j)
    const u16* qptr = qb + ((size_t)(b * S_ + q0 + w * 16 + l15)) * D_ + h * 64 + l4 * 8;
    bf16x8 aq0 = *(const bf16x8*)qptr;
    bf16x8 aq1 = *(const bf16x8*)(qptr + 32);

    int vl[4];
    for (int r = 0; r < 4; ++r) vl[r] = vlen[b * S_ + q0 + w * 16 + l4 * 4 + r];

    float m[4], lsum[4];
    f32x4 acc[4] = {};
    for (int r = 0; r < 4; ++r) { m[r] = -3.0e38f; lsum[r] = 0.f; }
    const float scale = 0.125f;

    for (int kt = 0; kt < 16; ++kt) {
        __syncthreads();   // previous iteration's LDS reads done
        // stage K tile [64 krows][64 d] (8KB): 2 x 16B per thread, source-swizzled
        for (int i = 0; i < 2; ++i) {
            int c = w * 64 + i * 256 + l;
            int kr = c >> 3, x = (c & 7) ^ (kr & 7);
            gload16(kb + ((size_t)(b * S_ + kt * 64 + kr)) * D_ + h * 64 + x * 8,
                    &k_lds[(w * 64 + i * 256) * 8]);
        }
        // stage Vt tile [64 d][64 k]
        for (int i = 0; i < 2; ++i) {
            int c = w * 64 + i * 256 + l;
            int dr = c >> 3, x = (c & 7) ^ (dr & 7);
            gload16(vt + ((size_t)bh * 64 + dr) * (size_t)S_ + kt * 64 + x * 8,
                    &v_lds[(w * 64 + i * 256) * 8]);
        }
        __syncthreads();   // staging complete (vmcnt drained at barrier)

        // QK^T: S[q][kcol], B-fragment = K row (nf*16 + l15), d-chunk (l4 + 4kk) swizzled
        f32x4 sc[4];
        for (int nf = 0; nf < 4; ++nf) {
            int kr = nf * 16 + l15, swz = kr & 7;
            bf16x8 bk0 = *(const bf16x8*)&k_lds[kr * 64 + ((l4) ^ swz) * 8];
            bf16x8 bk1 = *(const bf16x8*)&k_lds[kr * 64 + ((l4 + 4) ^ swz) * 8];
            f32x4 s = {0.f, 0.f, 0.f, 0.f};
            s = __builtin_amdgcn_mfma_f32_16x16x32_bf16(aq0, bk0, s, 0, 0, 0);
            s = __builtin_amdgcn_mfma_f32_16x16x32_bf16(aq1, bk1, s, 0, 0, 0);
            sc[nf] = s;
        }

        // scale + mask (exactly as reference: scale first, masked -> -1000.0)
        float p[4][4], pm[4];
        for (int r = 0; r < 4; ++r) pm[r] = -3.0e38f;
        for (int nf = 0; nf < 4; ++nf) {
            int kidx = kt * 64 + nf * 16 + l15;
            for (int r = 0; r < 4; ++r) {
                float v = (kidx < vl[r]) ? sc[nf][r] * scale : -1000.0f;
                p[nf][r] = v;
                pm[r] = fmaxf(pm[r], v);
            }
        }
        // row max across the 16-lane column group (rows live in regs, cols in l&15)
        for (int r = 0; r < 4; ++r) {
            float x = pm[r];
            x = fmaxf(x, __shfl_xor(x, 1, 64));
            x = fmaxf(x, __shfl_xor(x, 2, 64));
            x = fmaxf(x, __shfl_xor(x, 4, 64));
            x = fmaxf(x, __shfl_xor(x, 8, 64));
            pm[r] = x;
        }
        // online softmax update
        for (int r = 0; r < 4; ++r) {
            float mn = fmaxf(m[r], pm[r]);
            float corr = __expf(m[r] - mn);   // exp(-inf)=0 on first tile
            m[r] = mn;
            float s = 0.f;
            for (int nf = 0; nf < 4; ++nf) {
                float e = __expf(p[nf][r] - mn);
                p[nf][r] = e;
                s += e;
            }
            s += __shfl_xor(s, 1, 64);
            s += __shfl_xor(s, 2, 64);
            s += __shfl_xor(s, 4, 64);
            s += __shfl_xor(s, 8, 64);
            lsum[r] = lsum[r] * corr + s;
            for (int df = 0; df < 4; ++df) acc[df][r] *= corr;
        }
        // P -> LDS (bf16, swizzled), per-wave region; C-layout row=(l>>4)*4+r, col=nf*16+l15
        for (int nf = 0; nf < 4; ++nf)
            for (int r = 0; r < 4; ++r) {
                int row = l4 * 4 + r;
                int col = nf * 16 + l15;
                p_lds[w * 1024 + row * 64 + (col ^ ((row & 7) << 3))] = f2bf(p[nf][r]);
            }
        __syncthreads();   // P visible (and wave-internal lgkm drain)

        // PV: A = P row l15 (swizzled chunks), B = Vt row (df*16+l15)
        bf16x8 ap0, ap1;
        {
            int pr = l15, swz = pr & 7;
            ap0 = *(const bf16x8*)&p_lds[w * 1024 + pr * 64 + ((l4) ^ swz) * 8];
            ap1 = *(const bf16x8*)&p_lds[w * 1024 + pr * 64 + ((l4 + 4) ^ swz) * 8];
        }
        for (int df = 0; df < 4; ++df) {
            int vr = df * 16 + l15, swz = vr & 7;
            bf16x8 bv0 = *(const bf16x8*)&v_lds[vr * 64 + ((l4) ^ swz) * 8];
            bf16x8 bv1 = *(const bf16x8*)&v_lds[vr * 64 + ((l4 + 4) ^ swz) * 8];
            acc[df] = __builtin_amdgcn_mfma_f32_16x16x32_bf16(ap0, bv0, acc[df], 0, 0, 0);
            acc[df] = __builtin_amdgcn_mfma_f32_16x16x32_bf16(ap1, bv1, acc[df], 0, 0, 0);
        }
    }

    // epilogue: out[b, q, h*64 + d] = acc / lsum  (f32)
    for (int df = 0; df < 4; ++df)
        for (int r = 0; r < 4; ++r) {
            int orow = q0 + w * 16 + l4 * 4 + r;
            int ocol = h * 64 + df * 16 + l15;
            out[((size_t)(b * S_ + orow)) * D_ + ocol] = acc[df][r] / lsum[r];
        }
}

extern "C" void kernel_launch(void* const* d_in, const int* in_sizes, int n_in,
                              void* d_out, int out_size, void* d_ws, size_t ws_size,
                              hipStream_t stream) {
    const float* query = (const float*)d_in[0];
    const float* key   = (const float*)d_in[1];
    const float* value = (const float*)d_in[2];
    const int*   vlen  = (const int*)d_in[3];
    const float* Wq    = (const float*)d_in[4];
    const float* Wk    = (const float*)d_in[5];
    const float* Wv    = (const float*)d_in[6];
    float* out = (float*)d_out;

    // workspace layout (~73 MB): Wt x3 (2MB each) | xbuf (16MB, reused per tensor; later vt) | qb kb vb
    char* ws = (char*)d_ws;
    const size_t MB = 1024 * 1024;
    const size_t TSZ = (size_t)B_ * S_ * D_ * 2;   // 16,777,216 B
    u16* wtq = (u16*)(ws);
    u16* wtk = (u16*)(ws + 2 * MB);
    u16* wtv = (u16*)(ws + 4 * MB);
    u16* xb  = (u16*)(ws + 6 * MB);
    u16* qb  = (u16*)(ws + 6 * MB + TSZ);
    u16* kb  = (u16*)(ws + 6 * MB + 2 * TSZ);
    u16* vb  = (u16*)(ws + 6 * MB + 3 * TSZ);
    u16* vt  = xb;   // xb dead after the three GEMMs

    dim3 blk(256);
    int n8 = B_ * S_ * D_ / 8;

    transpose_w_kernel<<<dim3(32, 32), blk, 0, stream>>>(Wq, wtq);
    transpose_w_kernel<<<dim3(32, 32), blk, 0, stream>>>(Wk, wtk);
    transpose_w_kernel<<<dim3(32, 32), blk, 0, stream>>>(Wv, wtv);

    cvt_bf16_kernel<<<n8 / 256, blk, 0, stream>>>(query, xb, n8);
    gemm_bf16_kernel<<<dim3(64, 8), blk, 0, stream>>>(xb, wtq, qb);
    cvt_bf16_kernel<<<n8 / 256, blk, 0, stream>>>(key, xb, n8);
    gemm_bf16_kernel<<<dim3(64, 8), blk, 0, stream>>>(xb, wtk, kb);
    cvt_bf16_kernel<<<n8 / 256, blk, 0, stream>>>(value, xb, n8);
    gemm_bf16_kernel<<<dim3(64, 8), blk, 0, stream>>>(xb, wtv, vb);

    transpose_v_kernel<<<B_ * H_ * (S_ / 64), blk, 0, stream>>>(vb, vt);

    attn_kernel<<<dim3(B_ * H_, S_ / 64), blk, 0, stream>>>(qb, kb, vt, vlen, out);
}

// Round 2
// 208.286 us; speedup vs baseline: 1.1825x; 1.1825x over previous
//
#include <hip/hip_runtime.h>
#include <hip/hip_bf16.h>
#include <stdint.h>

// MHA: out = softmax_mask((X Wq)(X Wk)^T / sqrt(dh)) (X Wv), per-head, per-query valid_len mask.
// B=8 S=1024 D=1024 H=16 DH=64. f32 in/out, bf16 MFMA internally.

#define B_  8
#define S_  1024
#define D_  1024
#define H_  16
#define DH_ 64

typedef short bf16x8 __attribute__((ext_vector_type(8)));
typedef float f32x4  __attribute__((ext_vector_type(4)));
typedef unsigned short u16;
typedef uint32_t u32;
typedef u16 u16x8 __attribute__((ext_vector_type(8)));
typedef u16 u16x4 __attribute__((ext_vector_type(4)));

#define MASKVAL  (-1442.6950408889634f)            // -1000 * log2(e)
#define QSCALE   (0.18033688011112042f)            // (1/sqrt(64)) * log2(e)

union U4 { u32 u[4]; bf16x8 v; };

__device__ __forceinline__ u16 f2bf(float f) {
    union { float f; uint32_t u; } v; v.f = f;
    uint32_t u = v.u;
    return (u16)((u + 0x7FFFu + ((u >> 16) & 1u)) >> 16);   // RNE
}

__device__ __forceinline__ u32 cvtpk(float lo, float hi) {
    u32 r;
    asm("v_cvt_pk_bf16_f32 %0, %1, %2" : "=v"(r) : "v"(lo), "v"(hi));
    return r;
}

__device__ __forceinline__ void gload16(const void* g, const void* l) {
    __builtin_amdgcn_global_load_lds(
        (const __attribute__((address_space(1))) void*)g,
        (__attribute__((address_space(3))) void*)l, 16, 0, 0);
}

// ---------------- f32 -> bf16 elementwise convert (vectorized, G13) ----------------
__global__ void cvt_bf16_kernel(const float* __restrict__ in, u16* __restrict__ out, int n8) {
    int i = blockIdx.x * blockDim.x + threadIdx.x;
    if (i >= n8) return;
    const float4* p = (const float4*)in + (size_t)i * 2;
    float4 a = p[0], b = p[1];
    u16x8 r;
    r[0] = f2bf(a.x); r[1] = f2bf(a.y); r[2] = f2bf(a.z); r[3] = f2bf(a.w);
    r[4] = f2bf(b.x); r[5] = f2bf(b.y); r[6] = f2bf(b.z); r[7] = f2bf(b.w);
    *((u16x8*)out + i) = r;
}

// ---------------- W[k][n] f32 -> Wt[n][k] bf16 (LDS-tiled transpose) ----------------
__global__ void transpose_w_kernel(const float* __restrict__ W, u16* __restrict__ Wt) {
    __shared__ u16 tile[32 * 33];
    int k0 = blockIdx.y * 32, n0 = blockIdx.x * 32;
    int t = threadIdx.x;
    int c = t & 31;
    for (int p = 0; p < 4; ++p) {
        int r = p * 8 + (t >> 5);
        tile[r * 33 + c] = f2bf(W[(size_t)(k0 + r) * D_ + n0 + c]);
    }
    __syncthreads();
    int rn = t >> 3, c4 = t & 7;
    u16x4 v;
    for (int j = 0; j < 4; ++j) v[j] = tile[(c4 * 4 + j) * 33 + rn];
    *(u16x4*)(Wt + (size_t)(n0 + rn) * D_ + k0 + c4 * 4) = v;
}

// ---------------- bf16 GEMM: C[M=8192][1024] = (A[8192][1024] * Wt^T) * cmul ----------------
// m97 structure: 128x128 tile, BK=32, 4 waves each 64x64, global_load_lds(16B), 16 MFMA/K-step.
__global__ __launch_bounds__(256) void gemm_bf16_kernel(const u16* __restrict__ A,
                                                        const u16* __restrict__ Bt,
                                                        u16* __restrict__ C, float cmul) {
    __shared__ u16 lds_a[2][128 * 32];
    __shared__ u16 lds_b[2][128 * 32];
    const int t = threadIdx.x, w = t >> 6, l = t & 63;
    const int m0 = blockIdx.x * 128, n0 = blockIdx.y * 128;
    const int wr = w >> 1, wc = w & 1;
    const int l15 = l & 15, l4 = l >> 4;
    f32x4 acc[4][4] = {};

    auto stage = [&](int buf, int kt) {
        int k0 = kt * 32;
        for (int i = 0; i < 2; ++i) {
            int ch = w * 64 + i * 256 + l;
            int row = ch >> 2, x = ch & 3;
            gload16(A + (size_t)(m0 + row) * D_ + k0 + x * 8,
                    &lds_a[buf][(w * 64 + i * 256) * 8]);
        }
        for (int i = 0; i < 2; ++i) {
            int ch = w * 64 + i * 256 + l;
            int row = ch >> 2, x = ch & 3;
            gload16(Bt + (size_t)(n0 + row) * D_ + k0 + x * 8,
                    &lds_b[buf][(w * 64 + i * 256) * 8]);
        }
    };

    stage(0, 0);
    __syncthreads();
    int buf = 0;
    for (int kt = 0; kt < 32; ++kt) {
        if (kt + 1 < 32) stage(buf ^ 1, kt + 1);
        bf16x8 af[4], bfr[4];
        for (int mi = 0; mi < 4; ++mi)
            af[mi] = *(const bf16x8*)&lds_a[buf][(wr * 64 + mi * 16 + l15) * 32 + l4 * 8];
        for (int ni = 0; ni < 4; ++ni)
            bfr[ni] = *(const bf16x8*)&lds_b[buf][(wc * 64 + ni * 16 + l15) * 32 + l4 * 8];
        for (int mi = 0; mi < 4; ++mi)
            for (int ni = 0; ni < 4; ++ni)
                acc[mi][ni] = __builtin_amdgcn_mfma_f32_16x16x32_bf16(af[mi], bfr[ni], acc[mi][ni], 0, 0, 0);
        __syncthreads();
        buf ^= 1;
    }
    // epilogue: C/D layout col=lane&15, row=(lane>>4)*4+reg (m89-verified)
    for (int mi = 0; mi < 4; ++mi)
        for (int ni = 0; ni < 4; ++ni)
            for (int r = 0; r < 4; ++r) {
                int m = m0 + wr * 64 + mi * 16 + l4 * 4 + r;
                int n = n0 + wc * 64 + ni * 16 + l15;
                C[(size_t)m * D_ + n] = f2bf(acc[mi][ni][r] * cmul);
            }
}

// ---------------- vb [B,S,H,DH] -> vt [B,H,DH,S] (per-head transpose) ----------------
__global__ void transpose_v_kernel(const u16* __restrict__ vb, u16* __restrict__ vt) {
    __shared__ u16 t2[64 * 72];
    int bid = blockIdx.x;            // ((b*H + h)*16 + st)
    int st = bid & 15, bh = bid >> 4;
    int b = bh >> 4, h = bh & 15;
    int t = threadIdx.x;
    for (int p = 0; p < 2; ++p) {
        int c = p * 256 + t, r = c >> 3, x = c & 7;
        u16x8 val = *(const u16x8*)&vb[((size_t)(b * S_ + st * 64 + r)) * D_ + h * 64 + x * 8];
        *(u16x8*)&t2[r * 72 + x * 8] = val;
    }
    __syncthreads();
    int d = t >> 2, kc = t & 3;
    u16x8 o0, o1;
    for (int j = 0; j < 8; ++j) o0[j] = t2[(kc * 16 + j) * 72 + d];
    for (int j = 0; j < 8; ++j) o1[j] = t2[(kc * 16 + 8 + j) * 72 + d];
    size_t obase = ((size_t)bh * 64 + d) * (size_t)S_ + st * 64 + kc * 16;
    *(u16x8*)&vt[obase] = o0;
    *(u16x8*)&vt[obase + 8] = o1;
}

// ---------------- flash attention, swapped-operand (T12-style) ----------------
// grid (B*H, S/64); 4 waves x 16 q-rows. Swapped QK^T: S^T = mfma(K,Q) -> each lane owns
// one q-row (q=l&15), k = nf*16 + 4*(l>>4) + r. Softmax fully lane-local (+2 shfl_xor).
// P -> PV B-fragment via cvt_pk_bf16 + 16 bpermute (no LDS round trip). 1 barrier/tile.
__global__ __launch_bounds__(256) void attn_kernel(const u16* __restrict__ qb,
                                                   const u16* __restrict__ kb,
                                                   const u16* __restrict__ vt,
                                                   const int* __restrict__ vlen,
                                                   float* __restrict__ out) {
    __shared__ u16 smem[2][2][64 * 64];   // [buf][0=K,1=Vt][row*64 + swizzled chunk]

    const int t = threadIdx.x, w = t >> 6, l = t & 63;
    const int bh = blockIdx.x, b = bh >> 4, h = bh & 15;
    const int q0 = blockIdx.y * 64;
    const int l15 = l & 15, l4 = l >> 4;
    const int qrow = q0 + w * 16 + l15;

    // Q as B-fragment (col=l15=q, contraction d=l4*8+j); pre-scaled by QSCALE in GEMM
    const u16* qptr = qb + ((size_t)(b * S_ + qrow)) * D_ + h * 64 + l4 * 8;
    const bf16x8 bq0 = *(const bf16x8*)qptr;
    const bf16x8 bq1 = *(const bf16x8*)(qptr + 32);

    const int vlq = vlen[b * S_ + qrow];

    // P-redistribution shuffle sources: reader (a,b)=(l4>>1, l4&1) slot s pulls from
    // lane group 2b+(s>>1), word 4c + 2a + (s&1)  (verified map, see round-2 notes)
    const int srcA = l15 + ((l & 16) << 1);   // l15 + 32*(l4&1)   (groups 2b+0)
    const int srcB = srcA + 16;               //                   (groups 2b+1)
    const bool ahi = (l & 32) != 0;           // a = l4>>1

    const u16* kbase = kb + ((size_t)(b * S_)) * D_ + h * 64;
    const u16* vbase = vt + ((size_t)bh * 64) * (size_t)S_;

    float m = -3.0e38f, lsum = 0.f;
    f32x4 acc[4] = {};   // acc[df][r] = out[q=l15][d = df*16 + 4*l4 + r]

    auto stage = [&](int buf, int kt) {
        #pragma unroll
        for (int i = 0; i < 2; ++i) {
            int c = w * 64 + i * 256 + l;
            int kr = c >> 3, x = (c & 7) ^ (kr & 7);
            gload16(kbase + (size_t)(kt * 64 + kr) * D_ + x * 8,
                    &smem[buf][0][(w * 64 + i * 256) * 8]);
        }
        #pragma unroll
        for (int i = 0; i < 2; ++i) {
            int c = w * 64 + i * 256 + l;
            int dr = c >> 3, x = (c & 7) ^ (dr & 7);
            gload16(vbase + (size_t)dr * S_ + kt * 64 + x * 8,
                    &smem[buf][1][(w * 64 + i * 256) * 8]);
        }
    };

    stage(0, 0);
    __syncthreads();

    int buf = 0;
    for (int kt = 0; kt < 16; ++kt) {
        if (kt + 1 < 16) stage(buf ^ 1, kt + 1);

        // --- QK^T swapped: S^T[k][q] ---
        f32x4 sc[4];
        __builtin_amdgcn_s_setprio(1);
        #pragma unroll
        for (int nf = 0; nf < 4; ++nf) {
            int kr = nf * 16 + l15, swz = kr & 7;
            bf16x8 ak0 = *(const bf16x8*)&smem[buf][0][kr * 64 + ((l4 ^ swz) * 8)];
            bf16x8 ak1 = *(const bf16x8*)&smem[buf][0][kr * 64 + (((l4 + 4) ^ swz) * 8)];
            f32x4 s = {0.f, 0.f, 0.f, 0.f};
            s = __builtin_amdgcn_mfma_f32_16x16x32_bf16(ak0, bq0, s, 0, 0, 0);
            s = __builtin_amdgcn_mfma_f32_16x16x32_bf16(ak1, bq1, s, 0, 0, 0);
            sc[nf] = s;
        }
        __builtin_amdgcn_s_setprio(0);

        // --- mask + online softmax (lane-local; q=l15, k = kt*64 + nf*16 + 4*l4 + r) ---
        const int thr = vlq - kt * 64 - 4 * l4;
        float p[16];
        float pm = -3.0e38f;
        #pragma unroll
        for (int nf = 0; nf < 4; ++nf)
            #pragma unroll
            for (int r = 0; r < 4; ++r) {
                float y = ((nf * 16 + r) < thr) ? sc[nf][r] : MASKVAL;
                p[nf * 4 + r] = y;
                pm = fmaxf(pm, y);
            }
        pm = fmaxf(pm, __shfl_xor(pm, 16, 64));
        pm = fmaxf(pm, __shfl_xor(pm, 32, 64));
        float mn = fmaxf(m, pm);
        float corr = __builtin_amdgcn_exp2f(m - mn);
        m = mn;
        float rs = 0.f;
        #pragma unroll
        for (int i = 0; i < 16; ++i) {
            float e = __builtin_amdgcn_exp2f(p[i] - mn);
            p[i] = e;
            rs += e;
        }
        rs += __shfl_xor(rs, 16, 64);
        rs += __shfl_xor(rs, 32, 64);
        lsum = lsum * corr + rs;
        #pragma unroll
        for (int df = 0; df < 4; ++df) acc[df] *= corr;

        // --- pack P -> bf16 pairs; redistribute to P^T B-fragments ---
        u32 pw[8];
        #pragma unroll
        for (int nf = 0; nf < 4; ++nf) {
            pw[2 * nf]     = cvtpk(p[4 * nf + 0], p[4 * nf + 1]);
            pw[2 * nf + 1] = cvtpk(p[4 * nf + 2], p[4 * nf + 3]);
        }
        U4 pb0, pb1;
        {
            u32 w00 = (u32)__shfl((int)pw[0], srcA, 64);
            u32 w10 = (u32)__shfl((int)pw[2], srcA, 64);
            u32 w01 = (u32)__shfl((int)pw[1], srcA, 64);
            u32 w11 = (u32)__shfl((int)pw[3], srcA, 64);
            u32 w02 = (u32)__shfl((int)pw[0], srcB, 64);
            u32 w12 = (u32)__shfl((int)pw[2], srcB, 64);
            u32 w03 = (u32)__shfl((int)pw[1], srcB, 64);
            u32 w13 = (u32)__shfl((int)pw[3], srcB, 64);
            pb0.u[0] = ahi ? w10 : w00;
            pb0.u[1] = ahi ? w11 : w01;
            pb0.u[2] = ahi ? w12 : w02;
            pb0.u[3] = ahi ? w13 : w03;
        }
        {
            u32 w00 = (u32)__shfl((int)pw[4], srcA, 64);
            u32 w10 = (u32)__shfl((int)pw[6], srcA, 64);
            u32 w01 = (u32)__shfl((int)pw[5], srcA, 64);
            u32 w11 = (u32)__shfl((int)pw[7], srcA, 64);
            u32 w02 = (u32)__shfl((int)pw[4], srcB, 64);
            u32 w12 = (u32)__shfl((int)pw[6], srcB, 64);
            u32 w03 = (u32)__shfl((int)pw[5], srcB, 64);
            u32 w13 = (u32)__shfl((int)pw[7], srcB, 64);
            pb1.u[0] = ahi ? w10 : w00;
            pb1.u[1] = ahi ? w11 : w01;
            pb1.u[2] = ahi ? w12 : w02;
            pb1.u[3] = ahi ? w13 : w03;
        }

        // --- PV swapped: out^T[d][q] += mfma(Vt_frag, P_frag) ---
        __builtin_amdgcn_s_setprio(1);
        #pragma unroll
        for (int df = 0; df < 4; ++df) {
            int vr = df * 16 + l15, swz = vr & 7;
            bf16x8 av0 = *(const bf16x8*)&smem[buf][1][vr * 64 + ((l4 ^ swz) * 8)];
            bf16x8 av1 = *(const bf16x8*)&smem[buf][1][vr * 64 + (((l4 + 4) ^ swz) * 8)];
            acc[df] = __builtin_amdgcn_mfma_f32_16x16x32_bf16(av0, pb0.v, acc[df], 0, 0, 0);
            acc[df] = __builtin_amdgcn_mfma_f32_16x16x32_bf16(av1, pb1.v, acc[df], 0, 0, 0);
        }
        __builtin_amdgcn_s_setprio(0);

        __syncthreads();
        buf ^= 1;
    }

    // --- epilogue: transpose acc through LDS -> coalesced float4 stores ---
    const float inv = 1.0f / lsum;
    __syncthreads();                       // all tiles done; smem free for reuse
    float* ep = (float*)smem;              // per-wave region [16 q][68] f32
    #pragma unroll
    for (int df = 0; df < 4; ++df)
        #pragma unroll
        for (int r = 0; r < 4; ++r)
            ep[w * 1088 + l15 * 68 + df * 16 + 4 * l4 + r] = acc[df][r] * inv;
    __syncthreads();
    #pragma unroll
    for (int rr = 0; rr < 4; ++rr) {
        int row = l4 * 4 + rr;
        float4 vv = *(float4*)&ep[w * 1088 + row * 68 + l15 * 4];
        *(float4*)&out[((size_t)(b * S_ + q0 + w * 16 + row)) * D_ + h * 64 + l15 * 4] = vv;
    }
}

extern "C" void kernel_launch(void* const* d_in, const int* in_sizes, int n_in,
                              void* d_out, int out_size, void* d_ws, size_t ws_size,
                              hipStream_t stream) {
    const float* query = (const float*)d_in[0];
    const float* key   = (const float*)d_in[1];
    const float* value = (const float*)d_in[2];
    const int*   vlen  = (const int*)d_in[3];
    const float* Wq    = (const float*)d_in[4];
    const float* Wk    = (const float*)d_in[5];
    const float* Wv    = (const float*)d_in[6];
    float* out = (float*)d_out;

    // workspace layout (~73 MB): Wt x3 (2MB each) | xbuf (16MB, reused per tensor; later vt) | qb kb vb
    char* ws = (char*)d_ws;
    const size_t MB = 1024 * 1024;
    const size_t TSZ = (size_t)B_ * S_ * D_ * 2;   // 16,777,216 B
    u16* wtq = (u16*)(ws);
    u16* wtk = (u16*)(ws + 2 * MB);
    u16* wtv = (u16*)(ws + 4 * MB);
    u16* xb  = (u16*)(ws + 6 * MB);
    u16* qb  = (u16*)(ws + 6 * MB + TSZ);
    u16* kb  = (u16*)(ws + 6 * MB + 2 * TSZ);
    u16* vb  = (u16*)(ws + 6 * MB + 3 * TSZ);
    u16* vt  = xb;   // xb dead after the three GEMMs

    dim3 blk(256);
    int n8 = B_ * S_ * D_ / 8;

    transpose_w_kernel<<<dim3(32, 32), blk, 0, stream>>>(Wq, wtq);
    transpose_w_kernel<<<dim3(32, 32), blk, 0, stream>>>(Wk, wtk);
    transpose_w_kernel<<<dim3(32, 32), blk, 0, stream>>>(Wv, wtv);

    cvt_bf16_kernel<<<n8 / 256, blk, 0, stream>>>(query, xb, n8);
    gemm_bf16_kernel<<<dim3(64, 8), blk, 0, stream>>>(xb, wtq, qb, QSCALE);  // fold scale*log2e into Q
    cvt_bf16_kernel<<<n8 / 256, blk, 0, stream>>>(key, xb, n8);
    gemm_bf16_kernel<<<dim3(64, 8), blk, 0, stream>>>(xb, wtk, kb, 1.0f);
    cvt_bf16_kernel<<<n8 / 256, blk, 0, stream>>>(value, xb, n8);
    gemm_bf16_kernel<<<dim3(64, 8), blk, 0, stream>>>(xb, wtv, vb, 1.0f);

    transpose_v_kernel<<<B_ * H_ * (S_ / 64), blk, 0, stream>>>(vb, vt);

    attn_kernel<<<dim3(B_ * H_, S_ / 64), blk, 0, stream>>>(qb, kb, vt, vlen, out);
}